// Round 10
// baseline (202.769 us; speedup 1.0000x reference)
//
#include <hip/hip_runtime.h>
#include <hip/hip_bf16.h>

// Fused GATConv + proj + LayerNorm + ReLU. N=50000, E=800000, F_IN=128, H=4, C=16, D=128.
// CSR build is now ATOMIC-FREE at global scope (global atomics = 19G/s wall on gfx950,
// proven rounds 6/8/9). LDS-atomic bucket radix instead:
//   k_prep     : pack W/proj_w into bf16 hi/lo MFMA fragments; fold bias (no memsets needed)
//   k_xw_part1 : FUSED: (a) xp = x@W split-bf16 MFMA + logits; (b) per-2048-edge-block
//                LDS histogram of dst>>8 -> cnt[blk][bucket]
//   k_scanB    : 1 block: column scan cnt over blocks + bucket scan -> scatter bases, bb[]
//   k_part2    : re-read edges, LDS-atomic slot in (blk,bucket) run, write (src<<8)|dstLow
//   k_csr      : per bucket: LDS histogram exact node + LDS scan -> row_ptr + colsrc
//   k_agg2     : segment softmax + aggregation (4 edges per vmem wave-instruction)
//   k_proj     : aggr(bf16) @ proj_w^T + pb2, LayerNorm, ReLU (32 MFMA)

#define LEAKY(x) ((x) > 0.f ? (x) : 0.2f * (x))
#define CHUNK 2048
#define NBUK_PAD 256

typedef __attribute__((ext_vector_type(8))) short bf16x8;
typedef __attribute__((ext_vector_type(4))) float f32x4;

static __device__ __forceinline__ unsigned short f2bf_rne(float f) {
    unsigned u = __float_as_uint(f);
    return (unsigned short)((u + 0x7FFFu + ((u >> 16) & 1u)) >> 16);
}
static __device__ __forceinline__ float bf2f(unsigned short h) {
    return __uint_as_float(((unsigned)h) << 16);
}

// idx [0,8192): W frags; [8192,16384): proj_w frags; [16384,16512): pb2
__global__ __launch_bounds__(256) void k_prep(
    const float* __restrict__ W, const float* __restrict__ bias,
    const float* __restrict__ proj_w, const float* __restrict__ proj_b,
    unsigned short* __restrict__ Whf, unsigned short* __restrict__ Wlf,
    unsigned short* __restrict__ Phf, unsigned short* __restrict__ Plf,
    float* __restrict__ pb2)
{
    int idx = blockIdx.x * 256 + threadIdx.x;
    if (idx < 8192) {
        int j = idx & 7, lane = (idx >> 3) & 63, ts = idx >> 9;
        int t = ts >> 2, s = ts & 3;
        int k = s * 32 + ((lane >> 4) << 3) + j;
        int n = t * 16 + (lane & 15);
        float w = W[k * 64 + n];
        unsigned short wh = f2bf_rne(w);
        Whf[idx] = wh;
        Wlf[idx] = f2bf_rne(w - bf2f(wh));
    } else if (idx < 16384) {
        int i2 = idx - 8192;
        int j = i2 & 7, lane = (i2 >> 3) & 63, ts = i2 >> 9;
        int t = ts >> 1, s = ts & 1;
        int k = s * 32 + ((lane >> 4) << 3) + j;   // 0..63
        int d = t * 16 + (lane & 15);              // 0..127
        float w = proj_w[d * 64 + k];
        unsigned short wh = f2bf_rne(w);
        Phf[i2] = wh;
        Plf[i2] = f2bf_rne(w - bf2f(wh));
    } else if (idx < 16384 + 128) {
        int d = idx - 16384;
        float s = proj_b[d];
        for (int j = 0; j < 64; j++) s += bias[j] * proj_w[d * 64 + j];
        pb2[d] = s;
    }
}

// FUSED xw + part1. Every P-th block (bid%P==P-1) histograms one 2048-edge chunk
// by dst>>8 into LDS, then writes cnt[blk][bucket]. Other blocks do a 64-node xw tile.
__global__ __launch_bounds__(256) void k_xw_part1(
    const float* __restrict__ x,
    const unsigned short* __restrict__ Whf, const unsigned short* __restrict__ Wlf,
    const float* __restrict__ att_src, const float* __restrict__ att_dst,
    unsigned short* __restrict__ xp, float* __restrict__ a_src, float* __restrict__ a_dst,
    int n_nodes,
    const int* __restrict__ dst, int* __restrict__ cnt, int E,
    int P, int nbXw)
{
    int bid = blockIdx.x;
    int t = threadIdx.x;
    if (bid % P == P - 1) {
        // ---- part1: LDS histogram of dst>>8 ----
        __shared__ int hist[NBUK_PAD];
        hist[t] = 0;
        __syncthreads();
        int blk = bid / P;
        int e0 = blk * CHUNK;
#pragma unroll
        for (int i = 0; i < CHUNK / 256; i++) {
            int e = e0 + i * 256 + t;
            if (e < E) atomicAdd(&hist[dst[e] >> 8], 1);   // LDS atomic
        }
        __syncthreads();
        cnt[blk * NBUK_PAD + t] = hist[t];
        return;
    }
    // ---- xw path ----
    int xb = bid - bid / P;
    if (xb >= nbXw) return;
    int w = t >> 6, lane = t & 63;
    int mbase = xb * 64 + w * 16;
    int mrow = lane & 15, kg = lane >> 4;
    int node = mbase + mrow;
    if (node >= n_nodes) node = n_nodes - 1;   // clamp; fake rows never stored

    bf16x8 ah[4], al[4];
#pragma unroll
    for (int s = 0; s < 4; s++) {
        const float* px = x + (size_t)node * 128 + s * 32 + kg * 8;
        float4 v0 = *(const float4*)px;
        float4 v1 = *(const float4*)(px + 4);
        float f[8] = {v0.x, v0.y, v0.z, v0.w, v1.x, v1.y, v1.z, v1.w};
#pragma unroll
        for (int j = 0; j < 8; j++) {
            unsigned short h = f2bf_rne(f[j]);
            ah[s][j] = (short)h;
            al[s][j] = (short)f2bf_rne(f[j] - bf2f(h));
        }
    }

    f32x4 acc[4];
#pragma unroll
    for (int tt = 0; tt < 4; tt++) acc[tt] = (f32x4){0.f, 0.f, 0.f, 0.f};

#pragma unroll
    for (int tt = 0; tt < 4; tt++) {
#pragma unroll
        for (int s = 0; s < 4; s++) {
            size_t fi = (size_t)(((tt * 4 + s) * 64 + lane) * 8);
            bf16x8 bh = *(const bf16x8*)(Whf + fi);
            bf16x8 bl = *(const bf16x8*)(Wlf + fi);
            acc[tt] = __builtin_amdgcn_mfma_f32_16x16x32_bf16(ah[s], bh, acc[tt], 0, 0, 0);
            acc[tt] = __builtin_amdgcn_mfma_f32_16x16x32_bf16(ah[s], bl, acc[tt], 0, 0, 0);
            acc[tt] = __builtin_amdgcn_mfma_f32_16x16x32_bf16(al[s], bh, acc[tt], 0, 0, 0);
        }
    }

    // D layout: col=lane&15, row=(lane>>4)*4+reg. Tile tt == head tt.
#pragma unroll
    for (int tt = 0; tt < 4; tt++) {
        float asv = att_src[tt * 16 + mrow];
        float adv = att_dst[tt * 16 + mrow];
#pragma unroll
        for (int r = 0; r < 4; r++) {
            float v = acc[tt][r];
            int n2 = mbase + kg * 4 + r;
            bool ok = (n2 < n_nodes);
            if (ok) xp[(size_t)n2 * 64 + tt * 16 + mrow] = f2bf_rne(v);
            float ts = v * asv;
            float td = v * adv;
#pragma unroll
            for (int off = 8; off; off >>= 1) {
                ts += __shfl_xor(ts, off);
                td += __shfl_xor(td, off);
            }
            if (mrow == 0 && ok) {
                a_src[n2 * 4 + tt] = ts;
                a_dst[n2 * 4 + tt] = td;
            }
        }
    }
}

// 1 block. cnt[blk][b] -> global scatter base for (blk,b); bb[b] = bucket base;
// bb[256] = E; row_ptr[N] = E.
__global__ __launch_bounds__(256) void k_scanB(int* __restrict__ cnt, int* __restrict__ bb,
                                               int* __restrict__ row_ptr,
                                               int nchunk, int n_nodes, int E)
{
    __shared__ int sh[256];
    int t = threadIdx.x;
    int run = 0;
    for (int i = 0; i < nchunk; i++) {
        int v = cnt[i * NBUK_PAD + t];
        cnt[i * NBUK_PAD + t] = run;   // per-(blk,bucket) prefix within bucket
        run += v;
    }
    int tot = run;
    sh[t] = tot; __syncthreads();
    for (int off = 1; off < 256; off <<= 1) {
        int u = (t >= off) ? sh[t - off] : 0;
        __syncthreads();
        sh[t] += u;
        __syncthreads();
    }
    int base = sh[t] - tot;            // exclusive bucket base
    for (int i = 0; i < nchunk; i++) cnt[i * NBUK_PAD + t] += base;
    bb[t] = base;
    if (t == 255) bb[256] = sh[255];   // == E
    if (t == 0) row_ptr[n_nodes] = E;
}

// Scatter edges into bucket-partitioned order. Slot via LDS atomic on (blk,bucket) base.
// part[pos] = (src<<8) | (dst & 255)   (src < 65536, dst bucket implied by position)
__global__ __launch_bounds__(256) void k_part2(const int* __restrict__ src, const int* __restrict__ dst,
                                               const int* __restrict__ cnt,
                                               unsigned* __restrict__ part, int E)
{
    __shared__ int bases[NBUK_PAD];
    int t = threadIdx.x, blk = blockIdx.x;
    bases[t] = cnt[blk * NBUK_PAD + t];
    __syncthreads();
    int e0 = blk * CHUNK;
#pragma unroll
    for (int i = 0; i < CHUNK / 256; i++) {
        int e = e0 + i * 256 + t;
        if (e < E) {
            int d = dst[e];
            int s = src[e];
            int pos = atomicAdd(&bases[d >> 8], 1);   // LDS atomic
            part[pos] = ((unsigned)s << 8) | (unsigned)(d & 255);
        }
    }
}

// One block per bucket: exact-node histogram + LDS scan -> row_ptr; scatter src -> colsrc.
__global__ __launch_bounds__(256) void k_csr(const unsigned* __restrict__ part, const int* __restrict__ bb,
                                             int* __restrict__ row_ptr, int* __restrict__ colsrc,
                                             int n_nodes)
{
    __shared__ int hist[256], off[256], sh[256];
    int t = threadIdx.x, b = blockIdx.x;
    int e0 = bb[b], e1 = bb[b + 1];
    int m = e1 - e0;
    hist[t] = 0;
    __syncthreads();
    for (int i = t; i < m; i += 256)
        atomicAdd(&hist[part[e0 + i] & 255u], 1);     // LDS atomic
    __syncthreads();
    int v = hist[t];
    sh[t] = v; __syncthreads();
    for (int o = 1; o < 256; o <<= 1) {
        int u = (t >= o) ? sh[t - o] : 0;
        __syncthreads();
        sh[t] += u;
        __syncthreads();
    }
    int excl = sh[t] - v;
    off[t] = excl;
    int node = b * 256 + t;
    if (node < n_nodes) row_ptr[node] = e0 + excl;
    __syncthreads();
    for (int i = t; i < m; i += 256) {
        unsigned u = part[e0 + i];
        int pos = atomicAdd(&off[u & 255u], 1);       // LDS atomic
        colsrc[e0 + pos] = (int)(u >> 8);
    }
}

// Gather kernel: one node per wave. Wave covers 4 edges per vmem instruction:
// lane = (edge-parity = lane>>4) x (channel-group = lane&15, 4 bf16 channels each).
__global__ __launch_bounds__(256, 8) void k_agg2(
    const unsigned short* __restrict__ xp, const float* __restrict__ a_src, const float* __restrict__ a_dst,
    const int* __restrict__ row_ptr, const int* __restrict__ colsrc,
    unsigned short* __restrict__ aggr, int n_nodes)
{
    __shared__ int   sstage[4][64];       // 1 KB
    __shared__ float alpha_s[4][64][4];   // 4 KB
    int t = threadIdx.x, w = t >> 6, lane = t & 63;
    int cgrp = lane & 15;     // channels 4*cgrp .. 4*cgrp+3
    int epar = lane >> 4;     // edge parity 0..3
    int h = cgrp >> 2;        // head of my channels
    int n = blockIdx.x * 4 + w;
    if (n >= n_nodes) return;
    int rp0 = row_ptr[n], rp1 = row_ptr[n + 1];
    float4 ad4 = *(const float4*)&a_dst[(size_t)n * 4];
    float ax = 0.f, ay = 0.f, az = 0.f, aw = 0.f, den = 0.f;
    for (int base = rp0; base < rp1; base += 64) {
        int cnt = rp1 - base; if (cnt > 64) cnt = 64;
        int s = 0;
        float4 p = make_float4(0.f, 0.f, 0.f, 0.f);
        if (lane < cnt) {
            s = colsrc[base + lane];
            float4 as4 = *(const float4*)&a_src[(size_t)s * 4];
            p.x = __expf(LEAKY(as4.x + ad4.x));
            p.y = __expf(LEAKY(as4.y + ad4.y));
            p.z = __expf(LEAKY(as4.z + ad4.z));
            p.w = __expf(LEAKY(as4.w + ad4.w));
        }
        sstage[w][lane] = s;
        *(float4*)&alpha_s[w][lane][0] = p;
        // same-wave LDS write->read is in-order; no barrier needed.
        // padded entries (j >= cnt) have alpha 0 / s 0 -> contribute nothing.
        int iters = (cnt + 3) >> 2;
        for (int it = 0; it < iters; ++it) {
            int j = (it << 2) + epar;
            int sj = sstage[w][j];
            float aj = alpha_s[w][j][h];
            ushort4 v = *(const ushort4*)(xp + (size_t)((unsigned)sj * 64u + (cgrp << 2)));
            den += aj;
            ax += aj * bf2f(v.x);
            ay += aj * bf2f(v.y);
            az += aj * bf2f(v.z);
            aw += aj * bf2f(v.w);
        }
    }
    // combine the 4 edge-parity groups (lane^16 flips parity bit0, lane^32 bit1)
    ax += __shfl_xor(ax, 16); ax += __shfl_xor(ax, 32);
    ay += __shfl_xor(ay, 16); ay += __shfl_xor(ay, 32);
    az += __shfl_xor(az, 16); az += __shfl_xor(az, 32);
    aw += __shfl_xor(aw, 16); aw += __shfl_xor(aw, 32);
    den += __shfl_xor(den, 16); den += __shfl_xor(den, 32);
    if (lane < 16) {
        float inv = 1.f / (den + 1e-16f);
        ushort4 o;
        o.x = f2bf_rne(ax * inv);
        o.y = f2bf_rne(ay * inv);
        o.z = f2bf_rne(az * inv);
        o.w = f2bf_rne(aw * inv);
        *(ushort4*)(aggr + (size_t)n * 64 + (cgrp << 2)) = o;
    }
}

// proj + LN + ReLU: aggr is bf16 -> A fragments load directly (lo-term exactly 0),
// weights stay hi/lo split -> 2 MFMA per (tt,s) = 32 total, zero conversion VALU.
__global__ __launch_bounds__(256, 4) void k_proj(
    const unsigned short* __restrict__ aggr,
    const unsigned short* __restrict__ Phf, const unsigned short* __restrict__ Plf,
    const float* __restrict__ pb2, const float* __restrict__ gamma, const float* __restrict__ beta,
    float* __restrict__ out, int n_nodes)
{
    __shared__ float pb_s[128], g_s[128], b_s[128];
    int t = threadIdx.x;
    if (t < 128) { pb_s[t] = pb2[t]; g_s[t] = gamma[t]; b_s[t] = beta[t]; }
    __syncthreads();
    int w = t >> 6, lane = t & 63;
    int mbase = blockIdx.x * 64 + w * 16;
    int mrow = lane & 15, kg = lane >> 4;
    int node = mbase + mrow;
    if (node >= n_nodes) node = n_nodes - 1;

    bf16x8 ah[2];
#pragma unroll
    for (int s = 0; s < 2; s++) {
        ah[s] = *(const bf16x8*)(aggr + (size_t)node * 64 + s * 32 + kg * 8);
    }

    f32x4 acc[8];
#pragma unroll
    for (int tt = 0; tt < 8; tt++) acc[tt] = (f32x4){0.f, 0.f, 0.f, 0.f};
#pragma unroll
    for (int tt = 0; tt < 8; tt++) {
#pragma unroll
        for (int s = 0; s < 2; s++) {
            size_t fi = (size_t)(((tt * 2 + s) * 64 + lane) * 8);
            bf16x8 bh = *(const bf16x8*)(Phf + fi);
            bf16x8 bl = *(const bf16x8*)(Plf + fi);
            acc[tt] = __builtin_amdgcn_mfma_f32_16x16x32_bf16(ah[s], bh, acc[tt], 0, 0, 0);
            acc[tt] = __builtin_amdgcn_mfma_f32_16x16x32_bf16(ah[s], bl, acc[tt], 0, 0, 0);
        }
    }

    // D layout: d = tt*16 + (lane&15), node_row = kg*4 + r
#pragma unroll
    for (int r = 0; r < 4; r++) {
        int nr = mbase + kg * 4 + r;
        float vv[8];
        float S = 0.f, Q = 0.f;
#pragma unroll
        for (int tt = 0; tt < 8; tt++) {
            float v = acc[tt][r] + pb_s[tt * 16 + mrow];
            vv[tt] = v;
            S += v;
            Q += v * v;
        }
#pragma unroll
        for (int off = 8; off; off >>= 1) {
            S += __shfl_xor(S, off);
            Q += __shfl_xor(Q, off);
        }
        float mu  = S * (1.f / 128.f);
        float var = Q * (1.f / 128.f) - mu * mu;
        float inv = rsqrtf(var + 1e-5f);
        if (nr < n_nodes) {
#pragma unroll
            for (int tt = 0; tt < 8; tt++) {
                int d = tt * 16 + mrow;
                float o = fmaxf((vv[tt] - mu) * inv * g_s[d] + b_s[d], 0.f);
                out[(size_t)nr * 128 + d] = o;
            }
        }
    }
}

extern "C" void kernel_launch(void* const* d_in, const int* in_sizes, int n_in,
                              void* d_out, int out_size, void* d_ws, size_t ws_size,
                              hipStream_t stream)
{
    const float* x       = (const float*)d_in[0];
    const int*   ei      = (const int*)  d_in[1];
    const float* W       = (const float*)d_in[2];
    const float* att_src = (const float*)d_in[3];
    const float* att_dst = (const float*)d_in[4];
    const float* bias    = (const float*)d_in[5];
    const float* proj_w  = (const float*)d_in[6];
    const float* proj_b  = (const float*)d_in[7];
    const float* gamma   = (const float*)d_in[8];
    const float* beta    = (const float*)d_in[9];

    int N = in_sizes[0] / 128;
    int E = in_sizes[1] / 2;
    const int* srcIdx = ei;
    const int* dstIdx = ei + E;

    int nchunk = (E + CHUNK - 1) / CHUNK;          // edge chunks (part1/part2 blocks)
    int NBUK   = (N + 255) / 256;                  // node buckets (csr blocks)
    int nbXw   = (N + 63) / 64;

    char* ws = (char*)d_ws;
    unsigned short* xp   = (unsigned short*)ws; ws += (size_t)N * 64 * 2;
    unsigned short* aggr = (unsigned short*)ws; ws += (size_t)N * 64 * 2;
    float* a_src   = (float*)ws; ws += (size_t)N * 4 * 4;
    float* a_dst   = (float*)ws; ws += (size_t)N * 4 * 4;
    int*   row_ptr = (int*)ws;   ws += (size_t)(N + 1) * 4;
    int*   cnt     = (int*)ws;   ws += (size_t)nchunk * NBUK_PAD * 4;
    unsigned* part = (unsigned*)ws; ws += (size_t)E * 4;
    int*   colsrc  = (int*)ws;   ws += (size_t)E * 4;
    int*   bb      = (int*)ws;   ws += 257 * 4;
    unsigned short* Whf = (unsigned short*)ws; ws += 8192 * 2;
    unsigned short* Wlf = (unsigned short*)ws; ws += 8192 * 2;
    unsigned short* Phf = (unsigned short*)ws; ws += 8192 * 2;
    unsigned short* Plf = (unsigned short*)ws; ws += 8192 * 2;
    float* pb2 = (float*)ws; ws += 128 * 4;

    // interleave: one part1 block per (P-1) xw blocks; exactly nchunk part1 slots
    int P = (nbXw + nchunk - 1) / nchunk + 1;
    int totalFused = nchunk * P;

    k_prep<<<(16512 + 255) / 256, 256, 0, stream>>>(W, bias, proj_w, proj_b,
                                                    Whf, Wlf, Phf, Plf, pb2);
    k_xw_part1<<<totalFused, 256, 0, stream>>>(x, Whf, Wlf, att_src, att_dst,
                                               xp, a_src, a_dst, N,
                                               dstIdx, cnt, E, P, nbXw);
    k_scanB<<<1, 256, 0, stream>>>(cnt, bb, row_ptr, nchunk, N, E);
    k_part2<<<nchunk, 256, 0, stream>>>(srcIdx, dstIdx, cnt, part, E);
    k_csr<<<NBUK, 256, 0, stream>>>(part, bb, row_ptr, colsrc, N);
    k_agg2<<<(N + 3) / 4, 256, 0, stream>>>(xp, a_src, a_dst, row_ptr, colsrc, aggr, N);
    k_proj<<<(N + 63) / 64, 256, 0, stream>>>(aggr, Phf, Plf, pb2, gamma, beta, (float*)d_out, N);
}

// Round 11
// 88.779 us; speedup vs baseline: 2.2840x; 2.2840x over previous
//
#include <hip/hip_runtime.h>
#include <hip/hip_bf16.h>

// Fused GATConv + proj + LayerNorm + ReLU. N=50000, E=800000, F_IN=128, H=4, C=16, D=128.
// CSR build is ATOMIC-FREE at global scope (global atomics = 19G/s wall on gfx950,
// proven rounds 6/8/9). LDS-atomic bucket radix; scans fully parallel (round-10 lesson:
// a single-block serial chunk-scan is 123us of pointer-chase latency).
//   k_prep     : pack W/proj_w into bf16 hi/lo MFMA fragments; fold bias
//   k_xw_part1 : FUSED: (a) xp = x@W split-bf16 MFMA + logits; (b) per-2048-edge-block
//                LDS histogram of dst>>8 -> cnt[blk][bucket]
//   k_scanB1   : per-bucket column scan over chunks (256 blocks, LDS Hillis-Steele)
//   k_scanB2   : 1 tiny block: exclusive scan of bucket totals -> bb[]
//   k_part2    : re-read edges, LDS-atomic slot in (blk,bucket) run, write (src<<8)|dstLow
//   k_csr      : per bucket: LDS histogram exact node + LDS scan -> row_ptr + colsrc
//   k_agg2     : segment softmax + aggregation (4 edges per vmem wave-instruction)
//   k_proj     : aggr(bf16) @ proj_w^T + pb2, LayerNorm, ReLU (32 MFMA)

#define LEAKY(x) ((x) > 0.f ? (x) : 0.2f * (x))
#define CHUNK 2048
#define NBUK_PAD 256

typedef __attribute__((ext_vector_type(8))) short bf16x8;
typedef __attribute__((ext_vector_type(4))) float f32x4;

static __device__ __forceinline__ unsigned short f2bf_rne(float f) {
    unsigned u = __float_as_uint(f);
    return (unsigned short)((u + 0x7FFFu + ((u >> 16) & 1u)) >> 16);
}
static __device__ __forceinline__ float bf2f(unsigned short h) {
    return __uint_as_float(((unsigned)h) << 16);
}

// idx [0,8192): W frags; [8192,16384): proj_w frags; [16384,16512): pb2
__global__ __launch_bounds__(256) void k_prep(
    const float* __restrict__ W, const float* __restrict__ bias,
    const float* __restrict__ proj_w, const float* __restrict__ proj_b,
    unsigned short* __restrict__ Whf, unsigned short* __restrict__ Wlf,
    unsigned short* __restrict__ Phf, unsigned short* __restrict__ Plf,
    float* __restrict__ pb2)
{
    int idx = blockIdx.x * 256 + threadIdx.x;
    if (idx < 8192) {
        int j = idx & 7, lane = (idx >> 3) & 63, ts = idx >> 9;
        int t = ts >> 2, s = ts & 3;
        int k = s * 32 + ((lane >> 4) << 3) + j;
        int n = t * 16 + (lane & 15);
        float w = W[k * 64 + n];
        unsigned short wh = f2bf_rne(w);
        Whf[idx] = wh;
        Wlf[idx] = f2bf_rne(w - bf2f(wh));
    } else if (idx < 16384) {
        int i2 = idx - 8192;
        int j = i2 & 7, lane = (i2 >> 3) & 63, ts = i2 >> 9;
        int t = ts >> 1, s = ts & 1;
        int k = s * 32 + ((lane >> 4) << 3) + j;   // 0..63
        int d = t * 16 + (lane & 15);              // 0..127
        float w = proj_w[d * 64 + k];
        unsigned short wh = f2bf_rne(w);
        Phf[i2] = wh;
        Plf[i2] = f2bf_rne(w - bf2f(wh));
    } else if (idx < 16384 + 128) {
        int d = idx - 16384;
        float s = proj_b[d];
        for (int j = 0; j < 64; j++) s += bias[j] * proj_w[d * 64 + j];
        pb2[d] = s;
    }
}

// FUSED xw + part1. Every P-th block (bid%P==P-1) histograms one 2048-edge chunk
// by dst>>8 into LDS, then writes cnt[blk][bucket]. Other blocks do a 64-node xw tile.
__global__ __launch_bounds__(256) void k_xw_part1(
    const float* __restrict__ x,
    const unsigned short* __restrict__ Whf, const unsigned short* __restrict__ Wlf,
    const float* __restrict__ att_src, const float* __restrict__ att_dst,
    unsigned short* __restrict__ xp, float* __restrict__ a_src, float* __restrict__ a_dst,
    int n_nodes,
    const int* __restrict__ dst, int* __restrict__ cnt, int E,
    int P, int nbXw)
{
    int bid = blockIdx.x;
    int t = threadIdx.x;
    if (bid % P == P - 1) {
        // ---- part1: LDS histogram of dst>>8 ----
        __shared__ int hist[NBUK_PAD];
        hist[t] = 0;
        __syncthreads();
        int blk = bid / P;
        int e0 = blk * CHUNK;
#pragma unroll
        for (int i = 0; i < CHUNK / 256; i++) {
            int e = e0 + i * 256 + t;
            if (e < E) atomicAdd(&hist[dst[e] >> 8], 1);   // LDS atomic
        }
        __syncthreads();
        cnt[blk * NBUK_PAD + t] = hist[t];
        return;
    }
    // ---- xw path ----
    int xb = bid - bid / P;
    if (xb >= nbXw) return;
    int w = t >> 6, lane = t & 63;
    int mbase = xb * 64 + w * 16;
    int mrow = lane & 15, kg = lane >> 4;
    int node = mbase + mrow;
    if (node >= n_nodes) node = n_nodes - 1;   // clamp; fake rows never stored

    bf16x8 ah[4], al[4];
#pragma unroll
    for (int s = 0; s < 4; s++) {
        const float* px = x + (size_t)node * 128 + s * 32 + kg * 8;
        float4 v0 = *(const float4*)px;
        float4 v1 = *(const float4*)(px + 4);
        float f[8] = {v0.x, v0.y, v0.z, v0.w, v1.x, v1.y, v1.z, v1.w};
#pragma unroll
        for (int j = 0; j < 8; j++) {
            unsigned short h = f2bf_rne(f[j]);
            ah[s][j] = (short)h;
            al[s][j] = (short)f2bf_rne(f[j] - bf2f(h));
        }
    }

    f32x4 acc[4];
#pragma unroll
    for (int tt = 0; tt < 4; tt++) acc[tt] = (f32x4){0.f, 0.f, 0.f, 0.f};

#pragma unroll
    for (int tt = 0; tt < 4; tt++) {
#pragma unroll
        for (int s = 0; s < 4; s++) {
            size_t fi = (size_t)(((tt * 4 + s) * 64 + lane) * 8);
            bf16x8 bh = *(const bf16x8*)(Whf + fi);
            bf16x8 bl = *(const bf16x8*)(Wlf + fi);
            acc[tt] = __builtin_amdgcn_mfma_f32_16x16x32_bf16(ah[s], bh, acc[tt], 0, 0, 0);
            acc[tt] = __builtin_amdgcn_mfma_f32_16x16x32_bf16(ah[s], bl, acc[tt], 0, 0, 0);
            acc[tt] = __builtin_amdgcn_mfma_f32_16x16x32_bf16(al[s], bh, acc[tt], 0, 0, 0);
        }
    }

    // D layout: col=lane&15, row=(lane>>4)*4+reg. Tile tt == head tt.
#pragma unroll
    for (int tt = 0; tt < 4; tt++) {
        float asv = att_src[tt * 16 + mrow];
        float adv = att_dst[tt * 16 + mrow];
#pragma unroll
        for (int r = 0; r < 4; r++) {
            float v = acc[tt][r];
            int n2 = mbase + kg * 4 + r;
            bool ok = (n2 < n_nodes);
            if (ok) xp[(size_t)n2 * 64 + tt * 16 + mrow] = f2bf_rne(v);
            float ts = v * asv;
            float td = v * adv;
#pragma unroll
            for (int off = 8; off; off >>= 1) {
                ts += __shfl_xor(ts, off);
                td += __shfl_xor(td, off);
            }
            if (mrow == 0 && ok) {
                a_src[n2 * 4 + tt] = ts;
                a_dst[n2 * 4 + tt] = td;
            }
        }
    }
}

// Per-bucket column scan over chunks. Block b: exclusive-scan cnt[*][b] (nchunk <= 512)
// via 2x256 Hillis-Steele with carry; writes per-(chunk,bucket) prefix + bucket total.
__global__ __launch_bounds__(256) void k_scanB1(int* __restrict__ cnt, int* __restrict__ bt,
                                                int nchunk)
{
    __shared__ int sh[256];
    int t = threadIdx.x, b = blockIdx.x;
    int v0 = (t < nchunk) ? cnt[t * NBUK_PAD + b] : 0;
    int v1 = (t + 256 < nchunk) ? cnt[(t + 256) * NBUK_PAD + b] : 0;
    sh[t] = v0; __syncthreads();
    for (int off = 1; off < 256; off <<= 1) {
        int u = (t >= off) ? sh[t - off] : 0;
        __syncthreads();
        sh[t] += u;
        __syncthreads();
    }
    int incl0 = sh[t], tot0 = sh[255];
    __syncthreads();
    sh[t] = v1; __syncthreads();
    for (int off = 1; off < 256; off <<= 1) {
        int u = (t >= off) ? sh[t - off] : 0;
        __syncthreads();
        sh[t] += u;
        __syncthreads();
    }
    int incl1 = sh[t] + tot0;
    if (t < nchunk) cnt[t * NBUK_PAD + b] = incl0 - v0;
    if (t + 256 < nchunk) cnt[(t + 256) * NBUK_PAD + b] = incl1 - v1;
    if (t == 255) bt[b] = incl1;   // grand total of this bucket
}

// 1 tiny block: exclusive scan of bucket totals -> bb; bb[256]=E; row_ptr[N]=E.
__global__ __launch_bounds__(256) void k_scanB2(const int* __restrict__ bt, int* __restrict__ bb,
                                                int* __restrict__ row_ptr, int n_nodes, int E)
{
    __shared__ int sh[256];
    int t = threadIdx.x;
    int v = bt[t];
    sh[t] = v; __syncthreads();
    for (int off = 1; off < 256; off <<= 1) {
        int u = (t >= off) ? sh[t - off] : 0;
        __syncthreads();
        sh[t] += u;
        __syncthreads();
    }
    bb[t] = sh[t] - v;
    if (t == 255) bb[256] = sh[255];
    if (t == 0) row_ptr[n_nodes] = E;
}

// Scatter edges into bucket-partitioned order. Slot via LDS atomic on (blk,bucket) base.
// part[pos] = (src<<8) | (dst & 255)
__global__ __launch_bounds__(256) void k_part2(const int* __restrict__ src, const int* __restrict__ dst,
                                               const int* __restrict__ cnt, const int* __restrict__ bb,
                                               unsigned* __restrict__ part, int E)
{
    __shared__ int bases[NBUK_PAD];
    int t = threadIdx.x, blk = blockIdx.x;
    bases[t] = cnt[blk * NBUK_PAD + t] + bb[t];
    __syncthreads();
    int e0 = blk * CHUNK;
#pragma unroll
    for (int i = 0; i < CHUNK / 256; i++) {
        int e = e0 + i * 256 + t;
        if (e < E) {
            int d = dst[e];
            int s = src[e];
            int pos = atomicAdd(&bases[d >> 8], 1);   // LDS atomic
            part[pos] = ((unsigned)s << 8) | (unsigned)(d & 255);
        }
    }
}

// One block per bucket: exact-node histogram + LDS scan -> row_ptr; scatter src -> colsrc.
__global__ __launch_bounds__(256) void k_csr(const unsigned* __restrict__ part, const int* __restrict__ bb,
                                             int* __restrict__ row_ptr, int* __restrict__ colsrc,
                                             int n_nodes)
{
    __shared__ int hist[256], off[256], sh[256];
    int t = threadIdx.x, b = blockIdx.x;
    int e0 = bb[b], e1 = bb[b + 1];
    int m = e1 - e0;
    hist[t] = 0;
    __syncthreads();
    for (int i = t; i < m; i += 256)
        atomicAdd(&hist[part[e0 + i] & 255u], 1);     // LDS atomic
    __syncthreads();
    int v = hist[t];
    sh[t] = v; __syncthreads();
    for (int o = 1; o < 256; o <<= 1) {
        int u = (t >= o) ? sh[t - o] : 0;
        __syncthreads();
        sh[t] += u;
        __syncthreads();
    }
    int excl = sh[t] - v;
    off[t] = excl;
    int node = b * 256 + t;
    if (node < n_nodes) row_ptr[node] = e0 + excl;
    __syncthreads();
    for (int i = t; i < m; i += 256) {
        unsigned u = part[e0 + i];
        int pos = atomicAdd(&off[u & 255u], 1);       // LDS atomic
        colsrc[e0 + pos] = (int)(u >> 8);
    }
}

// Gather kernel: one node per wave. Wave covers 4 edges per vmem instruction:
// lane = (edge-parity = lane>>4) x (channel-group = lane&15, 4 bf16 channels each).
__global__ __launch_bounds__(256, 8) void k_agg2(
    const unsigned short* __restrict__ xp, const float* __restrict__ a_src, const float* __restrict__ a_dst,
    const int* __restrict__ row_ptr, const int* __restrict__ colsrc,
    unsigned short* __restrict__ aggr, int n_nodes)
{
    __shared__ int   sstage[4][64];       // 1 KB
    __shared__ float alpha_s[4][64][4];   // 4 KB
    int t = threadIdx.x, w = t >> 6, lane = t & 63;
    int cgrp = lane & 15;     // channels 4*cgrp .. 4*cgrp+3
    int epar = lane >> 4;     // edge parity 0..3
    int h = cgrp >> 2;        // head of my channels
    int n = blockIdx.x * 4 + w;
    if (n >= n_nodes) return;
    int rp0 = row_ptr[n], rp1 = row_ptr[n + 1];
    float4 ad4 = *(const float4*)&a_dst[(size_t)n * 4];
    float ax = 0.f, ay = 0.f, az = 0.f, aw = 0.f, den = 0.f;
    for (int base = rp0; base < rp1; base += 64) {
        int cnt = rp1 - base; if (cnt > 64) cnt = 64;
        int s = 0;
        float4 p = make_float4(0.f, 0.f, 0.f, 0.f);
        if (lane < cnt) {
            s = colsrc[base + lane];
            float4 as4 = *(const float4*)&a_src[(size_t)s * 4];
            p.x = __expf(LEAKY(as4.x + ad4.x));
            p.y = __expf(LEAKY(as4.y + ad4.y));
            p.z = __expf(LEAKY(as4.z + ad4.z));
            p.w = __expf(LEAKY(as4.w + ad4.w));
        }
        sstage[w][lane] = s;
        *(float4*)&alpha_s[w][lane][0] = p;
        // same-wave LDS write->read is in-order; no barrier needed.
        // padded entries (j >= cnt) have alpha 0 / s 0 -> contribute nothing.
        int iters = (cnt + 3) >> 2;
        for (int it = 0; it < iters; ++it) {
            int j = (it << 2) + epar;
            int sj = sstage[w][j];
            float aj = alpha_s[w][j][h];
            ushort4 v = *(const ushort4*)(xp + (size_t)((unsigned)sj * 64u + (cgrp << 2)));
            den += aj;
            ax += aj * bf2f(v.x);
            ay += aj * bf2f(v.y);
            az += aj * bf2f(v.z);
            aw += aj * bf2f(v.w);
        }
    }
    // combine the 4 edge-parity groups (lane^16 flips parity bit0, lane^32 bit1)
    ax += __shfl_xor(ax, 16); ax += __shfl_xor(ax, 32);
    ay += __shfl_xor(ay, 16); ay += __shfl_xor(ay, 32);
    az += __shfl_xor(az, 16); az += __shfl_xor(az, 32);
    aw += __shfl_xor(aw, 16); aw += __shfl_xor(aw, 32);
    den += __shfl_xor(den, 16); den += __shfl_xor(den, 32);
    if (lane < 16) {
        float inv = 1.f / (den + 1e-16f);
        ushort4 o;
        o.x = f2bf_rne(ax * inv);
        o.y = f2bf_rne(ay * inv);
        o.z = f2bf_rne(az * inv);
        o.w = f2bf_rne(aw * inv);
        *(ushort4*)(aggr + (size_t)n * 64 + (cgrp << 2)) = o;
    }
}

// proj + LN + ReLU: aggr is bf16 -> A fragments load directly (lo-term exactly 0),
// weights stay hi/lo split -> 2 MFMA per (tt,s) = 32 total, zero conversion VALU.
__global__ __launch_bounds__(256, 4) void k_proj(
    const unsigned short* __restrict__ aggr,
    const unsigned short* __restrict__ Phf, const unsigned short* __restrict__ Plf,
    const float* __restrict__ pb2, const float* __restrict__ gamma, const float* __restrict__ beta,
    float* __restrict__ out, int n_nodes)
{
    __shared__ float pb_s[128], g_s[128], b_s[128];
    int t = threadIdx.x;
    if (t < 128) { pb_s[t] = pb2[t]; g_s[t] = gamma[t]; b_s[t] = beta[t]; }
    __syncthreads();
    int w = t >> 6, lane = t & 63;
    int mbase = blockIdx.x * 64 + w * 16;
    int mrow = lane & 15, kg = lane >> 4;
    int node = mbase + mrow;
    if (node >= n_nodes) node = n_nodes - 1;

    bf16x8 ah[2];
#pragma unroll
    for (int s = 0; s < 2; s++) {
        ah[s] = *(const bf16x8*)(aggr + (size_t)node * 64 + s * 32 + kg * 8);
    }

    f32x4 acc[8];
#pragma unroll
    for (int tt = 0; tt < 8; tt++) acc[tt] = (f32x4){0.f, 0.f, 0.f, 0.f};
#pragma unroll
    for (int tt = 0; tt < 8; tt++) {
#pragma unroll
        for (int s = 0; s < 2; s++) {
            size_t fi = (size_t)(((tt * 2 + s) * 64 + lane) * 8);
            bf16x8 bh = *(const bf16x8*)(Phf + fi);
            bf16x8 bl = *(const bf16x8*)(Plf + fi);
            acc[tt] = __builtin_amdgcn_mfma_f32_16x16x32_bf16(ah[s], bh, acc[tt], 0, 0, 0);
            acc[tt] = __builtin_amdgcn_mfma_f32_16x16x32_bf16(ah[s], bl, acc[tt], 0, 0, 0);
        }
    }

    // D layout: d = tt*16 + (lane&15), node_row = kg*4 + r
#pragma unroll
    for (int r = 0; r < 4; r++) {
        int nr = mbase + kg * 4 + r;
        float vv[8];
        float S = 0.f, Q = 0.f;
#pragma unroll
        for (int tt = 0; tt < 8; tt++) {
            float v = acc[tt][r] + pb_s[tt * 16 + mrow];
            vv[tt] = v;
            S += v;
            Q += v * v;
        }
#pragma unroll
        for (int off = 8; off; off >>= 1) {
            S += __shfl_xor(S, off);
            Q += __shfl_xor(Q, off);
        }
        float mu  = S * (1.f / 128.f);
        float var = Q * (1.f / 128.f) - mu * mu;
        float inv = rsqrtf(var + 1e-5f);
        if (nr < n_nodes) {
#pragma unroll
            for (int tt = 0; tt < 8; tt++) {
                int d = tt * 16 + mrow;
                float o = fmaxf((vv[tt] - mu) * inv * g_s[d] + b_s[d], 0.f);
                out[(size_t)nr * 128 + d] = o;
            }
        }
    }
}

extern "C" void kernel_launch(void* const* d_in, const int* in_sizes, int n_in,
                              void* d_out, int out_size, void* d_ws, size_t ws_size,
                              hipStream_t stream)
{
    const float* x       = (const float*)d_in[0];
    const int*   ei      = (const int*)  d_in[1];
    const float* W       = (const float*)d_in[2];
    const float* att_src = (const float*)d_in[3];
    const float* att_dst = (const float*)d_in[4];
    const float* bias    = (const float*)d_in[5];
    const float* proj_w  = (const float*)d_in[6];
    const float* proj_b  = (const float*)d_in[7];
    const float* gamma   = (const float*)d_in[8];
    const float* beta    = (const float*)d_in[9];

    int N = in_sizes[0] / 128;
    int E = in_sizes[1] / 2;
    const int* srcIdx = ei;
    const int* dstIdx = ei + E;

    int nchunk = (E + CHUNK - 1) / CHUNK;          // edge chunks (part1/part2 blocks)
    int NBUK   = (N + 255) / 256;                  // node buckets (csr blocks)
    int nbXw   = (N + 63) / 64;

    char* ws = (char*)d_ws;
    unsigned short* xp   = (unsigned short*)ws; ws += (size_t)N * 64 * 2;
    unsigned short* aggr = (unsigned short*)ws; ws += (size_t)N * 64 * 2;
    float* a_src   = (float*)ws; ws += (size_t)N * 4 * 4;
    float* a_dst   = (float*)ws; ws += (size_t)N * 4 * 4;
    int*   row_ptr = (int*)ws;   ws += (size_t)(N + 1) * 4;
    int*   cnt     = (int*)ws;   ws += (size_t)nchunk * NBUK_PAD * 4;
    unsigned* part = (unsigned*)ws; ws += (size_t)E * 4;
    int*   colsrc  = (int*)ws;   ws += (size_t)E * 4;
    int*   bb      = (int*)ws;   ws += 257 * 4;
    int*   bt      = (int*)ws;   ws += 256 * 4;
    unsigned short* Whf = (unsigned short*)ws; ws += 8192 * 2;
    unsigned short* Wlf = (unsigned short*)ws; ws += 8192 * 2;
    unsigned short* Phf = (unsigned short*)ws; ws += 8192 * 2;
    unsigned short* Plf = (unsigned short*)ws; ws += 8192 * 2;
    float* pb2 = (float*)ws; ws += 128 * 4;

    // interleave: one part1 block per (P-1) xw blocks; exactly nchunk part1 slots
    int P = (nbXw + nchunk - 1) / nchunk + 1;
    int totalFused = nchunk * P;

    k_prep<<<(16512 + 255) / 256, 256, 0, stream>>>(W, bias, proj_w, proj_b,
                                                    Whf, Wlf, Phf, Plf, pb2);
    k_xw_part1<<<totalFused, 256, 0, stream>>>(x, Whf, Wlf, att_src, att_dst,
                                               xp, a_src, a_dst, N,
                                               dstIdx, cnt, E, P, nbXw);
    k_scanB1<<<256, 256, 0, stream>>>(cnt, bt, nchunk);
    k_scanB2<<<1, 256, 0, stream>>>(bt, bb, row_ptr, N, E);
    k_part2<<<nchunk, 256, 0, stream>>>(srcIdx, dstIdx, cnt, bb, part, E);
    k_csr<<<NBUK, 256, 0, stream>>>(part, bb, row_ptr, colsrc, N);
    k_agg2<<<(N + 3) / 4, 256, 0, stream>>>(xp, a_src, a_dst, row_ptr, colsrc, aggr, N);
    k_proj<<<(N + 63) / 64, 256, 0, stream>>>(aggr, Phf, Plf, pb2, gamma, beta, (float*)d_out, N);
}

// Round 12
// 85.725 us; speedup vs baseline: 2.3654x; 1.0356x over previous
//
#include <hip/hip_runtime.h>
#include <hip/hip_bf16.h>

// Fused GATConv + proj + LayerNorm + ReLU. N=50000, E=800000, F_IN=128, H=4, C=16, D=128.
// CSR build is ATOMIC-FREE at global scope (global atomics = 19G/s wall, rounds 6/8/9).
//   k_prep_part1 : FUSED: per-chunk LDS histogram of dst>>8 (bid<nchunk) + weight packing
//   k_scanB1     : per-bucket column scan over chunks (256 blocks, LDS Hillis-Steele)
//   k_scanB2     : 1 tiny block: exclusive scan of bucket totals -> bb[]
//   k_part2_xw   : FUSED: (a) scatter edges into bucket runs (LDS-atomic slots),
//                  (b) xp = x@W split-bf16 MFMA (LDS-staged coalesced x) + logits
//   k_csr        : per bucket: exact-node LDS histogram + scan -> row_ptr + colsrc
//   k_agg2       : segment softmax + aggregation; 8 edges per vmem instruction (ushort8)
//   k_proj       : aggr(bf16) @ proj_w^T + pb2, LayerNorm, ReLU (32 MFMA)

#define LEAKY(x) ((x) > 0.f ? (x) : 0.2f * (x))
#define CHUNK 2048
#define NBUK_PAD 256

typedef __attribute__((ext_vector_type(8))) short bf16x8;
typedef __attribute__((ext_vector_type(8))) unsigned short u16x8;
typedef __attribute__((ext_vector_type(4))) float f32x4;

static __device__ __forceinline__ unsigned short f2bf_rne(float f) {
    unsigned u = __float_as_uint(f);
    return (unsigned short)((u + 0x7FFFu + ((u >> 16) & 1u)) >> 16);
}
static __device__ __forceinline__ float bf2f(unsigned short h) {
    return __uint_as_float(((unsigned)h) << 16);
}

// bid < nchunk: LDS histogram of one 2048-edge chunk by dst>>8.
// bid >= nchunk: weight packing, idx-mapped as before.
__global__ __launch_bounds__(256) void k_prep_part1(
    const float* __restrict__ W, const float* __restrict__ bias,
    const float* __restrict__ proj_w, const float* __restrict__ proj_b,
    unsigned short* __restrict__ Whf, unsigned short* __restrict__ Wlf,
    unsigned short* __restrict__ Phf, unsigned short* __restrict__ Plf,
    float* __restrict__ pb2,
    const int* __restrict__ dst, int* __restrict__ cnt, int E, int nchunk)
{
    int bid = blockIdx.x, t = threadIdx.x;
    if (bid < nchunk) {
        __shared__ int hist[NBUK_PAD];
        hist[t] = 0;
        __syncthreads();
        int e0 = bid * CHUNK;
#pragma unroll
        for (int i = 0; i < CHUNK / 256; i++) {
            int e = e0 + i * 256 + t;
            if (e < E) atomicAdd(&hist[dst[e] >> 8], 1);   // LDS atomic
        }
        __syncthreads();
        cnt[bid * NBUK_PAD + t] = hist[t];
        return;
    }
    int idx = (bid - nchunk) * 256 + t;
    if (idx < 8192) {
        int j = idx & 7, lane = (idx >> 3) & 63, ts = idx >> 9;
        int tt = ts >> 2, s = ts & 3;
        int k = s * 32 + ((lane >> 4) << 3) + j;
        int n = tt * 16 + (lane & 15);
        float w = W[k * 64 + n];
        unsigned short wh = f2bf_rne(w);
        Whf[idx] = wh;
        Wlf[idx] = f2bf_rne(w - bf2f(wh));
    } else if (idx < 16384) {
        int i2 = idx - 8192;
        int j = i2 & 7, lane = (i2 >> 3) & 63, ts = i2 >> 9;
        int tt = ts >> 1, s = ts & 1;
        int k = s * 32 + ((lane >> 4) << 3) + j;
        int d = tt * 16 + (lane & 15);
        float w = proj_w[d * 64 + k];
        unsigned short wh = f2bf_rne(w);
        Phf[i2] = wh;
        Plf[i2] = f2bf_rne(w - bf2f(wh));
    } else if (idx < 16384 + 128) {
        int d = idx - 16384;
        float s = proj_b[d];
        for (int j = 0; j < 64; j++) s += bias[j] * proj_w[d * 64 + j];
        pb2[d] = s;
    }
}

// Per-bucket column scan over chunks (nchunk <= 512).
__global__ __launch_bounds__(256) void k_scanB1(int* __restrict__ cnt, int* __restrict__ bt,
                                                int nchunk)
{
    __shared__ int sh[256];
    int t = threadIdx.x, b = blockIdx.x;
    int v0 = (t < nchunk) ? cnt[t * NBUK_PAD + b] : 0;
    int v1 = (t + 256 < nchunk) ? cnt[(t + 256) * NBUK_PAD + b] : 0;
    sh[t] = v0; __syncthreads();
    for (int off = 1; off < 256; off <<= 1) {
        int u = (t >= off) ? sh[t - off] : 0;
        __syncthreads();
        sh[t] += u;
        __syncthreads();
    }
    int incl0 = sh[t], tot0 = sh[255];
    __syncthreads();
    sh[t] = v1; __syncthreads();
    for (int off = 1; off < 256; off <<= 1) {
        int u = (t >= off) ? sh[t - off] : 0;
        __syncthreads();
        sh[t] += u;
        __syncthreads();
    }
    int incl1 = sh[t] + tot0;
    if (t < nchunk) cnt[t * NBUK_PAD + b] = incl0 - v0;
    if (t + 256 < nchunk) cnt[(t + 256) * NBUK_PAD + b] = incl1 - v1;
    if (t == 255) bt[b] = incl1;
}

// 1 tiny block: exclusive scan of bucket totals -> bb; bb[256]=E; row_ptr[N]=E.
__global__ __launch_bounds__(256) void k_scanB2(const int* __restrict__ bt, int* __restrict__ bb,
                                                int* __restrict__ row_ptr, int n_nodes, int E)
{
    __shared__ int sh[256];
    int t = threadIdx.x;
    int v = bt[t];
    sh[t] = v; __syncthreads();
    for (int off = 1; off < 256; off <<= 1) {
        int u = (t >= off) ? sh[t - off] : 0;
        __syncthreads();
        sh[t] += u;
        __syncthreads();
    }
    bb[t] = sh[t] - v;
    if (t == 255) bb[256] = sh[255];
    if (t == 0) row_ptr[n_nodes] = E;
}

// FUSED part2 + xw. Every P-th block (bid%P==P-1) scatters one 2048-edge chunk into
// bucket runs; other blocks do a 64-node xw tile with LDS-staged coalesced x loads.
__global__ __launch_bounds__(256) void k_part2_xw(
    const int* __restrict__ src, const int* __restrict__ dst,
    const int* __restrict__ cnt, const int* __restrict__ bb,
    unsigned* __restrict__ part, int E,
    const float* __restrict__ x,
    const unsigned short* __restrict__ Whf, const unsigned short* __restrict__ Wlf,
    const float* __restrict__ att_src, const float* __restrict__ att_dst,
    unsigned short* __restrict__ xp, float* __restrict__ a_src, float* __restrict__ a_dst,
    int n_nodes, int P, int nbXw)
{
    __shared__ float xs[64][132];          // 33.8 KB (xw path)
    __shared__ int bases[NBUK_PAD];        // 1 KB (part2 path)
    int bid = blockIdx.x, t = threadIdx.x;
    if (bid % P == P - 1) {
        // ---- part2: scatter into bucket-partitioned order ----
        int blk = bid / P;
        bases[t] = cnt[blk * NBUK_PAD + t] + bb[t];
        __syncthreads();
        int e0 = blk * CHUNK;
#pragma unroll
        for (int i = 0; i < CHUNK / 256; i++) {
            int e = e0 + i * 256 + t;
            if (e < E) {
                int d = dst[e];
                int s = src[e];
                int pos = atomicAdd(&bases[d >> 8], 1);   // LDS atomic
                part[pos] = ((unsigned)s << 8) | (unsigned)(d & 255);
            }
        }
        return;
    }
    // ---- xw path ----
    int xb = bid - bid / P;
    if (xb >= nbXw) return;
    int xbase = xb * 64;
    // stage 64 rows x 128 f32 through LDS, fully coalesced
    for (int i = t; i < 64 * 32; i += 256) {
        int r = i >> 5, c = (i & 31) << 2;
        int gr = xbase + r; if (gr >= n_nodes) gr = n_nodes - 1;
        *(float4*)&xs[r][c] = *(const float4*)(x + (size_t)gr * 128 + c);
    }
    __syncthreads();
    int w = t >> 6, lane = t & 63;
    int mbase = xbase + w * 16;
    int mrow = lane & 15, kg = lane >> 4;
    int lrow = w * 16 + mrow;

    bf16x8 ah[4], al[4];
#pragma unroll
    for (int s = 0; s < 4; s++) {
        float4 v0 = *(const float4*)&xs[lrow][s * 32 + kg * 8];
        float4 v1 = *(const float4*)&xs[lrow][s * 32 + kg * 8 + 4];
        float f[8] = {v0.x, v0.y, v0.z, v0.w, v1.x, v1.y, v1.z, v1.w};
#pragma unroll
        for (int j = 0; j < 8; j++) {
            unsigned short h = f2bf_rne(f[j]);
            ah[s][j] = (short)h;
            al[s][j] = (short)f2bf_rne(f[j] - bf2f(h));
        }
    }

    f32x4 acc[4];
#pragma unroll
    for (int tt = 0; tt < 4; tt++) acc[tt] = (f32x4){0.f, 0.f, 0.f, 0.f};
#pragma unroll
    for (int tt = 0; tt < 4; tt++) {
#pragma unroll
        for (int s = 0; s < 4; s++) {
            size_t fi = (size_t)(((tt * 4 + s) * 64 + lane) * 8);
            bf16x8 bh = *(const bf16x8*)(Whf + fi);
            bf16x8 bl = *(const bf16x8*)(Wlf + fi);
            acc[tt] = __builtin_amdgcn_mfma_f32_16x16x32_bf16(ah[s], bh, acc[tt], 0, 0, 0);
            acc[tt] = __builtin_amdgcn_mfma_f32_16x16x32_bf16(ah[s], bl, acc[tt], 0, 0, 0);
            acc[tt] = __builtin_amdgcn_mfma_f32_16x16x32_bf16(al[s], bh, acc[tt], 0, 0, 0);
        }
    }

    // D layout: col=lane&15, row=(lane>>4)*4+reg. Tile tt == head tt.
#pragma unroll
    for (int tt = 0; tt < 4; tt++) {
        float asv = att_src[tt * 16 + mrow];
        float adv = att_dst[tt * 16 + mrow];
#pragma unroll
        for (int r = 0; r < 4; r++) {
            float v = acc[tt][r];
            int n2 = mbase + kg * 4 + r;
            bool ok = (n2 < n_nodes);
            if (ok) xp[(size_t)n2 * 64 + tt * 16 + mrow] = f2bf_rne(v);
            float ts = v * asv;
            float td = v * adv;
#pragma unroll
            for (int off = 8; off; off >>= 1) {
                ts += __shfl_xor(ts, off);
                td += __shfl_xor(td, off);
            }
            if (mrow == 0 && ok) {
                a_src[n2 * 4 + tt] = ts;
                a_dst[n2 * 4 + tt] = td;
            }
        }
    }
}

// One block per bucket: exact-node histogram + LDS scan -> row_ptr; scatter src -> colsrc.
__global__ __launch_bounds__(256) void k_csr(const unsigned* __restrict__ part, const int* __restrict__ bb,
                                             int* __restrict__ row_ptr, int* __restrict__ colsrc,
                                             int n_nodes)
{
    __shared__ int hist[256], off[256], sh[256];
    int t = threadIdx.x, b = blockIdx.x;
    int e0 = bb[b], e1 = bb[b + 1];
    int m = e1 - e0;
    hist[t] = 0;
    __syncthreads();
    for (int i = t; i < m; i += 256)
        atomicAdd(&hist[part[e0 + i] & 255u], 1);     // LDS atomic
    __syncthreads();
    int v = hist[t];
    sh[t] = v; __syncthreads();
    for (int o = 1; o < 256; o <<= 1) {
        int u = (t >= o) ? sh[t - o] : 0;
        __syncthreads();
        sh[t] += u;
        __syncthreads();
    }
    int excl = sh[t] - v;
    off[t] = excl;
    int node = b * 256 + t;
    if (node < n_nodes) row_ptr[node] = e0 + excl;
    __syncthreads();
    for (int i = t; i < m; i += 256) {
        unsigned u = part[e0 + i];
        int pos = atomicAdd(&off[u & 255u], 1);       // LDS atomic
        colsrc[e0 + pos] = (int)(u >> 8);
    }
}

// Gather kernel: one node per wave. Wave covers 8 edges per vmem instruction:
// lane = (edge-oct = lane>>3) x (channel-group = lane&7, 8 bf16 channels each).
__global__ __launch_bounds__(256, 8) void k_agg2(
    const unsigned short* __restrict__ xp, const float* __restrict__ a_src, const float* __restrict__ a_dst,
    const int* __restrict__ row_ptr, const int* __restrict__ colsrc,
    unsigned short* __restrict__ aggr, int n_nodes)
{
    __shared__ int   sstage[4][64];       // 1 KB
    __shared__ float alpha_s[4][64][4];   // 4 KB
    int t = threadIdx.x, w = t >> 6, lane = t & 63;
    int cgrp = lane & 7;      // channels 8*cgrp .. 8*cgrp+7
    int eoct = lane >> 3;     // edge slot 0..7
    int h = cgrp >> 1;        // head of my 8 channels (16 ch per head)
    int n = blockIdx.x * 4 + w;
    if (n >= n_nodes) return;
    int rp0 = row_ptr[n], rp1 = row_ptr[n + 1];
    float4 ad4 = *(const float4*)&a_dst[(size_t)n * 4];
    float acc[8] = {0.f, 0.f, 0.f, 0.f, 0.f, 0.f, 0.f, 0.f};
    float den = 0.f;
    for (int base = rp0; base < rp1; base += 64) {
        int cnt = rp1 - base; if (cnt > 64) cnt = 64;
        int s = 0;
        float4 p = make_float4(0.f, 0.f, 0.f, 0.f);
        if (lane < cnt) {
            s = colsrc[base + lane];
            float4 as4 = *(const float4*)&a_src[(size_t)s * 4];
            p.x = __expf(LEAKY(as4.x + ad4.x));
            p.y = __expf(LEAKY(as4.y + ad4.y));
            p.z = __expf(LEAKY(as4.z + ad4.z));
            p.w = __expf(LEAKY(as4.w + ad4.w));
        }
        sstage[w][lane] = s;
        *(float4*)&alpha_s[w][lane][0] = p;
        // same-wave LDS write->read is in-order; no barrier needed.
        // padded entries (j >= cnt) have alpha 0 / s 0 -> contribute nothing.
        int iters = (cnt + 7) >> 3;
        for (int it = 0; it < iters; ++it) {
            int j = (it << 3) + eoct;
            int sj = sstage[w][j];
            float aj = alpha_s[w][j][h];
            u16x8 v = *(const u16x8*)(xp + (size_t)((unsigned)sj * 64u + (cgrp << 3)));
            den += aj;
#pragma unroll
            for (int q = 0; q < 8; q++) acc[q] += aj * bf2f(v[q]);
        }
    }
    // reduce over the 8 edge-octs (lane bits 3,4,5)
#pragma unroll
    for (int q = 0; q < 8; q++) {
        acc[q] += __shfl_xor(acc[q], 8);
        acc[q] += __shfl_xor(acc[q], 16);
        acc[q] += __shfl_xor(acc[q], 32);
    }
    den += __shfl_xor(den, 8);
    den += __shfl_xor(den, 16);
    den += __shfl_xor(den, 32);
    if (eoct == 0) {
        float inv = 1.f / (den + 1e-16f);
        u16x8 o;
#pragma unroll
        for (int q = 0; q < 8; q++) o[q] = f2bf_rne(acc[q] * inv);
        *(u16x8*)(aggr + (size_t)n * 64 + (cgrp << 3)) = o;
    }
}

// proj + LN + ReLU: aggr is bf16 -> A fragments load directly (lo-term exactly 0),
// weights stay hi/lo split -> 2 MFMA per (tt,s) = 32 total, zero conversion VALU.
__global__ __launch_bounds__(256, 4) void k_proj(
    const unsigned short* __restrict__ aggr,
    const unsigned short* __restrict__ Phf, const unsigned short* __restrict__ Plf,
    const float* __restrict__ pb2, const float* __restrict__ gamma, const float* __restrict__ beta,
    float* __restrict__ out, int n_nodes)
{
    __shared__ float pb_s[128], g_s[128], b_s[128];
    int t = threadIdx.x;
    if (t < 128) { pb_s[t] = pb2[t]; g_s[t] = gamma[t]; b_s[t] = beta[t]; }
    __syncthreads();
    int w = t >> 6, lane = t & 63;
    int mbase = blockIdx.x * 64 + w * 16;
    int mrow = lane & 15, kg = lane >> 4;
    int node = mbase + mrow;
    if (node >= n_nodes) node = n_nodes - 1;

    bf16x8 ah[2];
#pragma unroll
    for (int s = 0; s < 2; s++) {
        ah[s] = *(const bf16x8*)(aggr + (size_t)node * 64 + s * 32 + kg * 8);
    }

    f32x4 acc[8];
#pragma unroll
    for (int tt = 0; tt < 8; tt++) acc[tt] = (f32x4){0.f, 0.f, 0.f, 0.f};
#pragma unroll
    for (int tt = 0; tt < 8; tt++) {
#pragma unroll
        for (int s = 0; s < 2; s++) {
            size_t fi = (size_t)(((tt * 2 + s) * 64 + lane) * 8);
            bf16x8 bh = *(const bf16x8*)(Phf + fi);
            bf16x8 bl = *(const bf16x8*)(Plf + fi);
            acc[tt] = __builtin_amdgcn_mfma_f32_16x16x32_bf16(ah[s], bh, acc[tt], 0, 0, 0);
            acc[tt] = __builtin_amdgcn_mfma_f32_16x16x32_bf16(ah[s], bl, acc[tt], 0, 0, 0);
        }
    }

    // D layout: d = tt*16 + (lane&15), node_row = kg*4 + r
#pragma unroll
    for (int r = 0; r < 4; r++) {
        int nr = mbase + kg * 4 + r;
        float vv[8];
        float S = 0.f, Q = 0.f;
#pragma unroll
        for (int tt = 0; tt < 8; tt++) {
            float v = acc[tt][r] + pb_s[tt * 16 + mrow];
            vv[tt] = v;
            S += v;
            Q += v * v;
        }
#pragma unroll
        for (int off = 8; off; off >>= 1) {
            S += __shfl_xor(S, off);
            Q += __shfl_xor(Q, off);
        }
        float mu  = S * (1.f / 128.f);
        float var = Q * (1.f / 128.f) - mu * mu;
        float inv = rsqrtf(var + 1e-5f);
        if (nr < n_nodes) {
#pragma unroll
            for (int tt = 0; tt < 8; tt++) {
                int d = tt * 16 + mrow;
                float o = fmaxf((vv[tt] - mu) * inv * g_s[d] + b_s[d], 0.f);
                out[(size_t)nr * 128 + d] = o;
            }
        }
    }
}

extern "C" void kernel_launch(void* const* d_in, const int* in_sizes, int n_in,
                              void* d_out, int out_size, void* d_ws, size_t ws_size,
                              hipStream_t stream)
{
    const float* x       = (const float*)d_in[0];
    const int*   ei      = (const int*)  d_in[1];
    const float* W       = (const float*)d_in[2];
    const float* att_src = (const float*)d_in[3];
    const float* att_dst = (const float*)d_in[4];
    const float* bias    = (const float*)d_in[5];
    const float* proj_w  = (const float*)d_in[6];
    const float* proj_b  = (const float*)d_in[7];
    const float* gamma   = (const float*)d_in[8];
    const float* beta    = (const float*)d_in[9];

    int N = in_sizes[0] / 128;
    int E = in_sizes[1] / 2;
    const int* srcIdx = ei;
    const int* dstIdx = ei + E;

    int nchunk = (E + CHUNK - 1) / CHUNK;          // edge chunks
    int NBUK   = (N + 255) / 256;                  // node buckets
    int nbXw   = (N + 63) / 64;
    int nbPrep = (16512 + 255) / 256;

    char* ws = (char*)d_ws;
    unsigned short* xp   = (unsigned short*)ws; ws += (size_t)N * 64 * 2;
    unsigned short* aggr = (unsigned short*)ws; ws += (size_t)N * 64 * 2;
    float* a_src   = (float*)ws; ws += (size_t)N * 4 * 4;
    float* a_dst   = (float*)ws; ws += (size_t)N * 4 * 4;
    int*   row_ptr = (int*)ws;   ws += (size_t)(N + 1) * 4;
    int*   cnt     = (int*)ws;   ws += (size_t)nchunk * NBUK_PAD * 4;
    unsigned* part = (unsigned*)ws; ws += (size_t)E * 4;
    int*   colsrc  = (int*)ws;   ws += (size_t)E * 4;
    int*   bb      = (int*)ws;   ws += 257 * 4;
    int*   bt      = (int*)ws;   ws += 256 * 4;
    unsigned short* Whf = (unsigned short*)ws; ws += 8192 * 2;
    unsigned short* Wlf = (unsigned short*)ws; ws += 8192 * 2;
    unsigned short* Phf = (unsigned short*)ws; ws += 8192 * 2;
    unsigned short* Plf = (unsigned short*)ws; ws += 8192 * 2;
    float* pb2 = (float*)ws; ws += 128 * 4;

    // part2/xw interleave: one part2 block per (P-1) xw blocks; exactly nchunk part2 slots
    int P = (nbXw + nchunk - 1) / nchunk + 1;
    int totalFused = nchunk * P;

    k_prep_part1<<<nchunk + nbPrep, 256, 0, stream>>>(W, bias, proj_w, proj_b,
                                                      Whf, Wlf, Phf, Plf, pb2,
                                                      dstIdx, cnt, E, nchunk);
    k_scanB1<<<256, 256, 0, stream>>>(cnt, bt, nchunk);
    k_scanB2<<<1, 256, 0, stream>>>(bt, bb, row_ptr, N, E);
    k_part2_xw<<<totalFused, 256, 0, stream>>>(srcIdx, dstIdx, cnt, bb, part, E,
                                               x, Whf, Wlf, att_src, att_dst,
                                               xp, a_src, a_dst, N, P, nbXw);
    k_csr<<<NBUK, 256, 0, stream>>>(part, bb, row_ptr, colsrc, N);
    k_agg2<<<(N + 3) / 4, 256, 0, stream>>>(xp, a_src, a_dst, row_ptr, colsrc, aggr, N);
    k_proj<<<(N + 63) / 64, 256, 0, stream>>>(aggr, Phf, Plf, pb2, gamma, beta, (float*)d_out, N);
}